// Round 6
// baseline (621.356 us; speedup 1.0000x reference)
//
#include <hip/hip_runtime.h>
#include <hip/hip_bf16.h>
#include <cstdint>
#include <cstddef>

#define N_LEVELS   16
#define LOG2_T     19
#define TABLE_SIZE (1u << LOG2_T)
#define HASH_MASK  (TABLE_SIZE - 1u)
#define PRIME1     2654435761u

#define CPB 64          // points per chunk
#define NCHUNK 8        // chunks per block
#define FROW 40         // feat row stride (ushort): [enc0..31, x, y, 0 x6]
#define HSTRIDE 264     // h row stride (ushort): 256 + 8 pad (m97-style mod-4 dw stride)
#define FSTRIDE 72      // fallback-only feat stride

typedef __attribute__((ext_vector_type(8))) short short8;
typedef __attribute__((ext_vector_type(4))) float floatx4;

__device__ __constant__ float c_res[N_LEVELS] = {
    16.f, 20.f, 25.f, 32.f, 40.f, 50.f, 64.f, 80.f,
    101.f, 128.f, 161.f, 203.f, 256.f, 322.f, 406.f, 512.f
};

__device__ __forceinline__ unsigned short f2bf(float x) {
    union { float f; uint32_t u; } v; v.f = x;
    const uint32_t u = v.u;
    return (unsigned short)((u + 0x7fffu + ((u >> 16) & 1u)) >> 16);  // RNE
}

__device__ __forceinline__ uint32_t pk_bf16(float a, float b) {
#if __has_builtin(__builtin_amdgcn_cvt_pk_bf16_f32)
    typedef __attribute__((ext_vector_type(2))) __bf16 bf16x2;
    bf16x2 v = __builtin_amdgcn_cvt_pk_bf16_f32(a, b);
    uint32_t u; __builtin_memcpy(&u, &v, 4); return u;
#else
    return (uint32_t)f2bf(a) | ((uint32_t)f2bf(b) << 16);
#endif
}

// ---------------- weight packing into MFMA A-operand fragments ----------------
__global__ void pack_weights(const float* __restrict__ W0,
                             const float* __restrict__ W1,
                             const float* __restrict__ W2,
                             unsigned short* __restrict__ ws)
{
    const int f = blockIdx.x;       // 0..167
    const int lane = threadIdx.x;   // 0..63
    const int q = lane >> 4, r = lane & 15;
    int layer, kt, nt;
    if (f < 32)       { layer = 0; kt = f >> 4;        nt = f & 15; }
    else if (f < 160) { layer = 1; kt = (f - 32) >> 4; nt = (f - 32) & 15; }
    else              { layer = 2; kt = f - 160;       nt = 0; }
    unsigned short vals[8];
    #pragma unroll
    for (int j = 0; j < 8; ++j) {
        const int k = kt * 32 + q * 8 + j;
        const int n = nt * 16 + r;
        float v = 0.f;
        if (layer == 0) {
            if (k < 32)       v = W0[(2 + k) * 256 + n];
            else if (k == 32) v = W0[0 * 256 + n];
            else if (k == 33) v = W0[1 * 256 + n];
        } else if (layer == 1) {
            v = W1[k * 256 + n];
        } else {
            if (n < 3) v = W2[k * 3 + n];
        }
        vals[j] = f2bf(v);
    }
    uint4 pk;
    pk.x = (uint32_t)vals[0] | ((uint32_t)vals[1] << 16);
    pk.y = (uint32_t)vals[2] | ((uint32_t)vals[3] << 16);
    pk.z = (uint32_t)vals[4] | ((uint32_t)vals[5] << 16);
    pk.w = (uint32_t)vals[6] | ((uint32_t)vals[7] << 16);
    *(uint4*)(ws + (size_t)f * 1024 + lane * 8) = pk;
}

// ---------------- table fp32 -> packed bf16 ----------------
__global__ __launch_bounds__(256, 8)
void convert_table(const float* __restrict__ emb, uint32_t* __restrict__ tbl, int nentries)
{
    const int i = blockIdx.x * 256 + threadIdx.x;
    const int e0 = i * 4;
    if (e0 + 3 >= nentries) {
        for (int e = e0; e < nentries; ++e)
            tbl[e] = pk_bf16(emb[2 * e], emb[2 * e + 1]);
        return;
    }
    const float4* s4 = (const float4*)emb;
    const float4 a = s4[2 * i];
    const float4 b = s4[2 * i + 1];
    uint4 o;
    o.x = pk_bf16(a.x, a.y);
    o.y = pk_bf16(a.z, a.w);
    o.z = pk_bf16(b.x, b.y);
    o.w = pk_bf16(b.z, b.w);
    *(uint4*)(tbl + e0) = o;
}

// ---------------- pipelined encode helpers (4 threads/point, 4 levels each) ----------------
struct EncState {
    float x, y;
    float wx[4], wy[4];
    uint32_t g[4][4];   // [level_i][corner 00,01,10,11]
};

__device__ __forceinline__ void enc_issue(const uint32_t* __restrict__ tbl,
                                          const float* __restrict__ coord,
                                          int gp, int ek, EncState& s)
{
    const float2 cxy = *(const float2*)(coord + 2 * gp);
    s.x = fminf(fmaxf(cxy.x, -1.f), 1.f);
    s.y = fminf(fmaxf(cxy.y, -1.f), 1.f);
    #pragma unroll
    for (int i = 0; i < 4; ++i) {
        const int l = 4 * ek + i;
        const float res  = c_res[l];
        const float grid = 2.0f / res;             // IEEE div (matches ref exactly)
        const float invg = res * 0.5f;             // exact
        const float tx = (s.x + 1.0f) / grid;      // IEEE div feeds floor -> exact cell match
        const float ty = (s.y + 1.0f) / grid;
        const int bx = (int)floorf(tx);
        const int by = (int)floorf(ty);
        const float vx = (float)bx * grid - 1.0f;
        const float vy = (float)by * grid - 1.0f;
        s.wx[i] = (s.x - vx) * invg;
        s.wy[i] = (s.y - vy) * invg;
        const uint32_t* tab = tbl + (size_t)l * TABLE_SIZE;
        const uint32_t ux0 = (uint32_t)bx, ux1 = (uint32_t)(bx + 1);
        const uint32_t hy0 = (uint32_t)by * PRIME1;
        const uint32_t hy1 = (uint32_t)(by + 1) * PRIME1;
        s.g[i][0] = tab[(ux0 ^ hy0) & HASH_MASK];
        s.g[i][1] = tab[(ux0 ^ hy1) & HASH_MASK];
        s.g[i][2] = tab[(ux1 ^ hy0) & HASH_MASK];
        s.g[i][3] = tab[(ux1 ^ hy1) & HASH_MASK];
    }
}

__device__ __forceinline__ void enc_commit(unsigned short (*feat)[FROW],
                                           int ep, int ek, const EncState& s)
{
    if (ek == 0) {
        *(uint32_t*)&feat[ep][32] = pk_bf16(s.x, s.y);
        *(uint32_t*)&feat[ep][34] = 0u;
        *(uint32_t*)&feat[ep][36] = 0u;
        *(uint32_t*)&feat[ep][38] = 0u;
    }
    #pragma unroll
    for (int i = 0; i < 4; ++i) {
        const uint32_t u00 = s.g[i][0], u01 = s.g[i][1], u10 = s.g[i][2], u11 = s.g[i][3];
        const float e00x = __uint_as_float(u00 << 16), e00y = __uint_as_float(u00 & 0xffff0000u);
        const float e01x = __uint_as_float(u01 << 16), e01y = __uint_as_float(u01 & 0xffff0000u);
        const float e10x = __uint_as_float(u10 << 16), e10y = __uint_as_float(u10 & 0xffff0000u);
        const float e11x = __uint_as_float(u11 << 16), e11y = __uint_as_float(u11 & 0xffff0000u);
        const float wx = s.wx[i], wy = s.wy[i];
        const float owx = 1.f - wx, owy = 1.f - wy;
        const float f0 = (e00x * owx + e10x * wx) * owy + (e01x * owx + e11x * wx) * wy;
        const float f1 = (e00y * owx + e10y * wx) * owy + (e01y * owx + e11y * wx) * wy;
        *(uint32_t*)&feat[ep][8 * ek + 2 * i] = pk_bf16(f0, f1);
    }
}

// ---------------- fused, chunk-pipelined encode + MLP ----------------
__global__ __launch_bounds__(256, 3)
void fused_pipe(const float* __restrict__ coord,
                const uint32_t* __restrict__ tbl,
                const unsigned short* __restrict__ wpack,
                const float* __restrict__ b0,
                const float* __restrict__ b1,
                const float* __restrict__ b2,
                float* __restrict__ out, int npoints, int nchunks)
{
    __shared__ unsigned short feat[2][CPB][FROW];  // 10.2 KB double buffer
    __shared__ unsigned short h[CPB][HSTRIDE];     // 33.8 KB

    const int t = threadIdx.x;
    const int wave = t >> 6, lane = t & 63;
    const int q = lane >> 4, r = lane & 15;
    const int ep = t >> 2, ek = t & 3;             // encoder point / level-group

    const unsigned short* w0p = wpack;
    const unsigned short* w1p = wpack + 32 * 1024;
    const unsigned short* w2p = wpack + 160 * 1024;

    const int chunk0 = blockIdx.x * NCHUNK;
    if (chunk0 >= nchunks) return;

    EncState s;
    // prologue: encode chunk0 into feat[0]
    enc_issue(tbl, coord, min(chunk0 * CPB + ep, npoints - 1), ek, s);
    enc_commit(feat[0], ep, ek, s);
    __syncthreads();

    for (int c = 0; c < NCHUNK; ++c) {
        const int chunk = chunk0 + c;
        if (chunk >= nchunks) break;               // block-uniform
        const int cur = c & 1;
        const bool have_next = (c + 1 < NCHUNK) && (chunk + 1 < nchunks);

        // ---- A: issue next chunk's gathers (results land during MLP) ----
        if (have_next)
            enc_issue(tbl, coord, min((chunk + 1) * CPB + ep, npoints - 1), ek, s);

        const int p0 = chunk * CPB;

        // ---- B: layer 0 (K=64 padded) -> h0[point][neuron] ----
        {
            floatx4 acc[4][4];
            #pragma unroll
            for (int mti = 0; mti < 4; ++mti)
                #pragma unroll
                for (int nt = 0; nt < 4; ++nt)
                    acc[mti][nt] = floatx4{0.f, 0.f, 0.f, 0.f};

            short8 a[4], b[4];
            #pragma unroll
            for (int mti = 0; mti < 4; ++mti)
                a[mti] = *(const short8*)(w0p + (size_t)(0 * 16 + wave * 4 + mti) * 1024 + lane * 8);
            #pragma unroll
            for (int nt = 0; nt < 4; ++nt)
                b[nt] = *(const short8*)&feat[cur][16 * nt + r][q * 8];
            #pragma unroll
            for (int mti = 0; mti < 4; ++mti)
                #pragma unroll
                for (int nt = 0; nt < 4; ++nt)
                    acc[mti][nt] = __builtin_amdgcn_mfma_f32_16x16x32_bf16(a[mti], b[nt], acc[mti][nt], 0, 0, 0);

            #pragma unroll
            for (int mti = 0; mti < 4; ++mti)
                a[mti] = *(const short8*)(w0p + (size_t)(1 * 16 + wave * 4 + mti) * 1024 + lane * 8);
            #pragma unroll
            for (int nt = 0; nt < 4; ++nt)
                b[nt] = (q == 0) ? *(const short8*)&feat[cur][16 * nt + r][32]
                                 : short8{0,0,0,0,0,0,0,0};
            #pragma unroll
            for (int mti = 0; mti < 4; ++mti)
                #pragma unroll
                for (int nt = 0; nt < 4; ++nt)
                    acc[mti][nt] = __builtin_amdgcn_mfma_f32_16x16x32_bf16(a[mti], b[nt], acc[mti][nt], 0, 0, 0);

            #pragma unroll
            for (int mti = 0; mti < 4; ++mti) {
                const int col = (wave * 4 + mti) * 16 + 4 * q;
                const float4 bias = *(const float4*)&b0[col];
                #pragma unroll
                for (int nt = 0; nt < 4; ++nt) {
                    const floatx4 a4 = acc[mti][nt];
                    uint2 v;
                    v.x = pk_bf16(fmaxf(a4[0] + bias.x, 0.f), fmaxf(a4[1] + bias.y, 0.f));
                    v.y = pk_bf16(fmaxf(a4[2] + bias.z, 0.f), fmaxf(a4[3] + bias.w, 0.f));
                    *(uint2*)&h[16 * nt + r][col] = v;
                }
            }
        }
        __syncthreads();

        // ---- layer 1 (256 -> 256) ----
        {
            floatx4 acc[4][4];
            #pragma unroll
            for (int mti = 0; mti < 4; ++mti)
                #pragma unroll
                for (int nt = 0; nt < 4; ++nt)
                    acc[mti][nt] = floatx4{0.f, 0.f, 0.f, 0.f};
            #pragma unroll 2
            for (int kt = 0; kt < 8; ++kt) {
                short8 a[4], b[4];
                #pragma unroll
                for (int mti = 0; mti < 4; ++mti)
                    a[mti] = *(const short8*)(w1p + (size_t)(kt * 16 + wave * 4 + mti) * 1024 + lane * 8);
                #pragma unroll
                for (int nt = 0; nt < 4; ++nt)
                    b[nt] = *(const short8*)&h[16 * nt + r][kt * 32 + q * 8];
                #pragma unroll
                for (int mti = 0; mti < 4; ++mti)
                    #pragma unroll
                    for (int nt = 0; nt < 4; ++nt)
                        acc[mti][nt] = __builtin_amdgcn_mfma_f32_16x16x32_bf16(a[mti], b[nt], acc[mti][nt], 0, 0, 0);
            }
            __syncthreads();   // all reads of h0 done before overwrite
            #pragma unroll
            for (int mti = 0; mti < 4; ++mti) {
                const int col = (wave * 4 + mti) * 16 + 4 * q;
                const float4 bias = *(const float4*)&b1[col];
                #pragma unroll
                for (int nt = 0; nt < 4; ++nt) {
                    const floatx4 a4 = acc[mti][nt];
                    uint2 v;
                    v.x = pk_bf16(fmaxf(a4[0] + bias.x, 0.f), fmaxf(a4[1] + bias.y, 0.f));
                    v.y = pk_bf16(fmaxf(a4[2] + bias.z, 0.f), fmaxf(a4[3] + bias.w, 0.f));
                    *(uint2*)&h[16 * nt + r][col] = v;
                }
            }
        }
        __syncthreads();

        // ---- layer 2 (256 -> 3), sigmoid, store ----
        {
            floatx4 acc = floatx4{0.f, 0.f, 0.f, 0.f};
            #pragma unroll
            for (int kt = 0; kt < 8; ++kt) {
                const short8 a = *(const short8*)(w2p + (size_t)kt * 1024 + lane * 8);
                const short8 b = *(const short8*)&h[16 * wave + r][kt * 32 + q * 8];
                acc = __builtin_amdgcn_mfma_f32_16x16x32_bf16(a, b, acc, 0, 0, 0);
            }
            if (q == 0) {
                const int gp = p0 + 16 * wave + r;
                if (gp < npoints) {
                    #pragma unroll
                    for (int reg = 0; reg < 3; ++reg) {
                        const float sv = acc[reg] + b2[reg];
                        out[(size_t)gp * 3 + reg] = 1.f / (1.f + expf(-sv));
                    }
                }
            }
        }

        // ---- C: commit next chunk's features ----
        if (have_next)
            enc_commit(feat[cur ^ 1], ep, ek, s);
        __syncthreads();
    }
}

// ---------------- fused fallback (fp32 table, no big ws needed) ----------------
__global__ __launch_bounds__(256, 2)
void fused_ngp_mlp(const float* __restrict__ coord,
                   const float* __restrict__ emb,
                   const unsigned short* __restrict__ wpack,
                   const float* __restrict__ b0,
                   const float* __restrict__ b1,
                   const float* __restrict__ b2,
                   float* __restrict__ out, int npoints)
{
    __shared__ unsigned short feat[64][FSTRIDE];
    __shared__ unsigned short h[64][HSTRIDE];

    const int t = threadIdx.x;
    const int p0 = blockIdx.x * 64;
    const int wave = t >> 6;
    const int lane = t & 63;
    const int q = lane >> 4, r = lane & 15;

    {
        const int p = t >> 2;
        const int k = t & 3;
        const int gp = min(p0 + p, npoints - 1);
        float x = coord[2 * gp + 0];
        float y = coord[2 * gp + 1];
        x = fminf(fmaxf(x, -1.f), 1.f);
        y = fminf(fmaxf(y, -1.f), 1.f);
        if (k == 0) {
            feat[p][32] = f2bf(x); feat[p][33] = f2bf(y);
            *(uint32_t*)&feat[p][34] = 0u;
            *(uint32_t*)&feat[p][36] = 0u;
            *(uint32_t*)&feat[p][38] = 0u;
        } else {
            const uint4 z = {0u, 0u, 0u, 0u};
            *(uint4*)&feat[p][40 + 8 * (k - 1)] = z;
        }
        #pragma unroll
        for (int i = 0; i < 4; ++i) {
            const int l = 4 * k + i;
            const float res  = c_res[l];
            const float grid = 2.0f / res;
            const float invg = res * 0.5f;
            const float tx = (x + 1.0f) / grid;
            const float ty = (y + 1.0f) / grid;
            const int bx = (int)floorf(tx);
            const int by = (int)floorf(ty);
            const float vx = (float)bx * grid - 1.0f;
            const float vy = (float)by * grid - 1.0f;
            const float wx = (x - vx) * invg;
            const float wy = (y - vy) * invg;
            const float2* tab = (const float2*)emb + (size_t)l * TABLE_SIZE;
            const uint32_t ux0 = (uint32_t)bx, ux1 = (uint32_t)(bx + 1);
            const uint32_t hy0 = (uint32_t)by * PRIME1;
            const uint32_t hy1 = (uint32_t)(by + 1) * PRIME1;
            const float2 e00 = tab[(ux0 ^ hy0) & HASH_MASK];
            const float2 e01 = tab[(ux0 ^ hy1) & HASH_MASK];
            const float2 e10 = tab[(ux1 ^ hy0) & HASH_MASK];
            const float2 e11 = tab[(ux1 ^ hy1) & HASH_MASK];
            const float owx = 1.f - wx, owy = 1.f - wy;
            const float f0 = (e00.x * owx + e10.x * wx) * owy + (e01.x * owx + e11.x * wx) * wy;
            const float f1 = (e00.y * owx + e10.y * wx) * owy + (e01.y * owx + e11.y * wx) * wy;
            *(uint32_t*)&feat[p][8 * k + 2 * i] = pk_bf16(f0, f1);
        }
    }
    __syncthreads();

    const unsigned short* w0p = wpack;
    const unsigned short* w1p = wpack + 32 * 1024;
    const unsigned short* w2p = wpack + 160 * 1024;

    {
        floatx4 acc[4][4];
        #pragma unroll
        for (int mti = 0; mti < 4; ++mti)
            #pragma unroll
            for (int nt = 0; nt < 4; ++nt)
                acc[mti][nt] = floatx4{0.f, 0.f, 0.f, 0.f};
        #pragma unroll
        for (int kt = 0; kt < 2; ++kt) {
            short8 a[4], b[4];
            #pragma unroll
            for (int mti = 0; mti < 4; ++mti)
                a[mti] = *(const short8*)(w0p + (size_t)(kt * 16 + wave * 4 + mti) * 1024 + lane * 8);
            #pragma unroll
            for (int nt = 0; nt < 4; ++nt)
                b[nt] = *(const short8*)&feat[16 * nt + r][kt * 32 + q * 8];
            #pragma unroll
            for (int mti = 0; mti < 4; ++mti)
                #pragma unroll
                for (int nt = 0; nt < 4; ++nt)
                    acc[mti][nt] = __builtin_amdgcn_mfma_f32_16x16x32_bf16(a[mti], b[nt], acc[mti][nt], 0, 0, 0);
        }
        #pragma unroll
        for (int mti = 0; mti < 4; ++mti) {
            const int col = (wave * 4 + mti) * 16 + 4 * q;
            const float4 bias = *(const float4*)&b0[col];
            #pragma unroll
            for (int nt = 0; nt < 4; ++nt) {
                const floatx4 a4 = acc[mti][nt];
                uint2 v;
                v.x = pk_bf16(fmaxf(a4[0] + bias.x, 0.f), fmaxf(a4[1] + bias.y, 0.f));
                v.y = pk_bf16(fmaxf(a4[2] + bias.z, 0.f), fmaxf(a4[3] + bias.w, 0.f));
                *(uint2*)&h[16 * nt + r][col] = v;
            }
        }
    }
    __syncthreads();

    {
        floatx4 acc[4][4];
        #pragma unroll
        for (int mti = 0; mti < 4; ++mti)
            #pragma unroll
            for (int nt = 0; nt < 4; ++nt)
                acc[mti][nt] = floatx4{0.f, 0.f, 0.f, 0.f};
        #pragma unroll 2
        for (int kt = 0; kt < 8; ++kt) {
            short8 a[4], b[4];
            #pragma unroll
            for (int mti = 0; mti < 4; ++mti)
                a[mti] = *(const short8*)(w1p + (size_t)(kt * 16 + wave * 4 + mti) * 1024 + lane * 8);
            #pragma unroll
            for (int nt = 0; nt < 4; ++nt)
                b[nt] = *(const short8*)&h[16 * nt + r][kt * 32 + q * 8];
            #pragma unroll
            for (int mti = 0; mti < 4; ++mti)
                #pragma unroll
                for (int nt = 0; nt < 4; ++nt)
                    acc[mti][nt] = __builtin_amdgcn_mfma_f32_16x16x32_bf16(a[mti], b[nt], acc[mti][nt], 0, 0, 0);
        }
        __syncthreads();
        #pragma unroll
        for (int mti = 0; mti < 4; ++mti) {
            const int col = (wave * 4 + mti) * 16 + 4 * q;
            const float4 bias = *(const float4*)&b1[col];
            #pragma unroll
            for (int nt = 0; nt < 4; ++nt) {
                const floatx4 a4 = acc[mti][nt];
                uint2 v;
                v.x = pk_bf16(fmaxf(a4[0] + bias.x, 0.f), fmaxf(a4[1] + bias.y, 0.f));
                v.y = pk_bf16(fmaxf(a4[2] + bias.z, 0.f), fmaxf(a4[3] + bias.w, 0.f));
                *(uint2*)&h[16 * nt + r][col] = v;
            }
        }
    }
    __syncthreads();

    {
        floatx4 acc = floatx4{0.f, 0.f, 0.f, 0.f};
        #pragma unroll
        for (int kt = 0; kt < 8; ++kt) {
            const short8 a = *(const short8*)(w2p + (size_t)kt * 1024 + lane * 8);
            const short8 b = *(const short8*)&h[16 * wave + r][kt * 32 + q * 8];
            acc = __builtin_amdgcn_mfma_f32_16x16x32_bf16(a, b, acc, 0, 0, 0);
        }
        if (q == 0) {
            const int gp = p0 + 16 * wave + r;
            if (gp < npoints) {
                #pragma unroll
                for (int reg = 0; reg < 3; ++reg) {
                    const float s = acc[reg] + b2[reg];
                    out[(size_t)gp * 3 + reg] = 1.f / (1.f + expf(-s));
                }
            }
        }
    }
}

extern "C" void kernel_launch(void* const* d_in, const int* in_sizes, int n_in,
                              void* d_out, int out_size, void* d_ws, size_t ws_size,
                              hipStream_t stream) {
    const float* coord = (const float*)d_in[0];
    const float* emb   = (const float*)d_in[1];
    const float* W0    = (const float*)d_in[2];
    const float* b0    = (const float*)d_in[3];
    const float* W1    = (const float*)d_in[4];
    const float* b1    = (const float*)d_in[5];
    const float* W2    = (const float*)d_in[6];
    const float* b2    = (const float*)d_in[7];
    float* out = (float*)d_out;

    const int npoints  = in_sizes[0] / 2;
    const int nentries = N_LEVELS * TABLE_SIZE;

    const size_t pack_bytes = 168u * 1024u * 2u;     // 344 KB
    const size_t tbl_bytes  = (size_t)nentries * 4u; // 33.5 MB

    unsigned short* wpack = (unsigned short*)d_ws;

    hipLaunchKernelGGL(pack_weights, dim3(168), dim3(64), 0, stream, W0, W1, W2, wpack);

    const int nchunks = (npoints + CPB - 1) / CPB;

    if (ws_size >= pack_bytes + tbl_bytes) {
        uint32_t* tbl = (uint32_t*)((char*)d_ws + pack_bytes);
        hipLaunchKernelGGL(convert_table, dim3((nentries / 4 + 255) / 256), dim3(256), 0, stream,
                           emb, tbl, nentries);
        const int grid = (nchunks + NCHUNK - 1) / NCHUNK;
        hipLaunchKernelGGL(fused_pipe, dim3(grid), dim3(256), 0, stream,
                           coord, tbl, wpack, b0, b1, b2, out, npoints, nchunks);
    } else {
        hipLaunchKernelGGL(fused_ngp_mlp, dim3(nchunks), dim3(256), 0, stream,
                           coord, emb, wpack, b0, b1, b2, out, npoints);
    }
}

// Round 7
// 575.972 us; speedup vs baseline: 1.0788x; 1.0788x over previous
//
#include <hip/hip_runtime.h>
#include <hip/hip_bf16.h>
#include <cstdint>
#include <cstddef>

#define N_LEVELS   16
#define LOG2_T     19
#define TABLE_SIZE (1u << LOG2_T)
#define HASH_MASK  (TABLE_SIZE - 1u)
#define PRIME1     2654435761u

#define CPB 64          // points per chunk
#define NCHUNK 8        // chunks per block
#define FROW 40         // feat row stride (ushort): [enc0..31, x, y, 0 x6]
#define HSTRIDE 264     // h row stride (ushort): 256 + 8 pad
#define FSTRIDE 72      // fallback-only feat stride

typedef __attribute__((ext_vector_type(8))) short short8;
typedef __attribute__((ext_vector_type(4))) float floatx4;

__device__ __constant__ float c_res[N_LEVELS] = {
    16.f, 20.f, 25.f, 32.f, 40.f, 50.f, 64.f, 80.f,
    101.f, 128.f, 161.f, 203.f, 256.f, 322.f, 406.f, 512.f
};

// Block-wide barrier WITHOUT the vmcnt(0) drain __syncthreads() forces.
// All cross-wave handoff in fused_pipe is through LDS (feat/h), so only
// lgkmcnt must drain; in-flight global gathers survive the barrier.
#define BARRIER_LGKM() do { \
    __asm__ volatile("s_waitcnt lgkmcnt(0)" ::: "memory"); \
    __builtin_amdgcn_s_barrier(); \
    __asm__ volatile("" ::: "memory"); \
} while (0)

__device__ __forceinline__ unsigned short f2bf(float x) {
    union { float f; uint32_t u; } v; v.f = x;
    const uint32_t u = v.u;
    return (unsigned short)((u + 0x7fffu + ((u >> 16) & 1u)) >> 16);  // RNE
}

__device__ __forceinline__ uint32_t pk_bf16(float a, float b) {
#if __has_builtin(__builtin_amdgcn_cvt_pk_bf16_f32)
    typedef __attribute__((ext_vector_type(2))) __bf16 bf16x2;
    bf16x2 v = __builtin_amdgcn_cvt_pk_bf16_f32(a, b);
    uint32_t u; __builtin_memcpy(&u, &v, 4); return u;
#else
    return (uint32_t)f2bf(a) | ((uint32_t)f2bf(b) << 16);
#endif
}

// ---------------- weight packing into MFMA A-operand fragments ----------------
__global__ void pack_weights(const float* __restrict__ W0,
                             const float* __restrict__ W1,
                             const float* __restrict__ W2,
                             unsigned short* __restrict__ ws)
{
    const int f = blockIdx.x;       // 0..167
    const int lane = threadIdx.x;   // 0..63
    const int q = lane >> 4, r = lane & 15;
    int layer, kt, nt;
    if (f < 32)       { layer = 0; kt = f >> 4;        nt = f & 15; }
    else if (f < 160) { layer = 1; kt = (f - 32) >> 4; nt = (f - 32) & 15; }
    else              { layer = 2; kt = f - 160;       nt = 0; }
    unsigned short vals[8];
    #pragma unroll
    for (int j = 0; j < 8; ++j) {
        const int k = kt * 32 + q * 8 + j;
        const int n = nt * 16 + r;
        float v = 0.f;
        if (layer == 0) {
            if (k < 32)       v = W0[(2 + k) * 256 + n];
            else if (k == 32) v = W0[0 * 256 + n];
            else if (k == 33) v = W0[1 * 256 + n];
        } else if (layer == 1) {
            v = W1[k * 256 + n];
        } else {
            if (n < 3) v = W2[k * 3 + n];
        }
        vals[j] = f2bf(v);
    }
    uint4 pk;
    pk.x = (uint32_t)vals[0] | ((uint32_t)vals[1] << 16);
    pk.y = (uint32_t)vals[2] | ((uint32_t)vals[3] << 16);
    pk.z = (uint32_t)vals[4] | ((uint32_t)vals[5] << 16);
    pk.w = (uint32_t)vals[6] | ((uint32_t)vals[7] << 16);
    *(uint4*)(ws + (size_t)f * 1024 + lane * 8) = pk;
}

// ---------------- table fp32 -> packed bf16 ----------------
__global__ __launch_bounds__(256, 8)
void convert_table(const float* __restrict__ emb, uint32_t* __restrict__ tbl, int nentries)
{
    const int i = blockIdx.x * 256 + threadIdx.x;
    const int e0 = i * 4;
    if (e0 + 3 >= nentries) {
        for (int e = e0; e < nentries; ++e)
            tbl[e] = pk_bf16(emb[2 * e], emb[2 * e + 1]);
        return;
    }
    const float4* s4 = (const float4*)emb;
    const float4 a = s4[2 * i];
    const float4 b = s4[2 * i + 1];
    uint4 o;
    o.x = pk_bf16(a.x, a.y);
    o.y = pk_bf16(a.z, a.w);
    o.z = pk_bf16(b.x, b.y);
    o.w = pk_bf16(b.z, b.w);
    *(uint4*)(tbl + e0) = o;
}

// ---------------- pipelined encode helpers (4 threads/point, 4 levels each) ----------------
// Pipeline state kept deliberately tiny: clamped coords + 16 raw gather words.
// wx/wy are recomputed at commit (VALU is cheaper than spilled registers).
__device__ __forceinline__ void enc_issue(uint32_t (&g)[16], const uint32_t* __restrict__ tbl,
                                          float x, float y, int ek, const float (&gridv)[4])
{
    #pragma unroll
    for (int i = 0; i < 4; ++i) {
        const int l = 4 * ek + i;
        const float grid = gridv[i];
        const int bx = (int)floorf((x + 1.0f) / grid);   // IEEE div -> exact cell match
        const int by = (int)floorf((y + 1.0f) / grid);
        const uint32_t* tab = tbl + (size_t)l * TABLE_SIZE;
        const uint32_t ux0 = (uint32_t)bx, ux1 = (uint32_t)(bx + 1);
        const uint32_t hy0 = (uint32_t)by * PRIME1;
        const uint32_t hy1 = (uint32_t)(by + 1) * PRIME1;
        g[4 * i + 0] = tab[(ux0 ^ hy0) & HASH_MASK];
        g[4 * i + 1] = tab[(ux0 ^ hy1) & HASH_MASK];
        g[4 * i + 2] = tab[(ux1 ^ hy0) & HASH_MASK];
        g[4 * i + 3] = tab[(ux1 ^ hy1) & HASH_MASK];
    }
}

__device__ __forceinline__ void enc_commit(unsigned short (*feat)[FROW], int ep, int ek,
                                           const uint32_t (&g)[16], float x, float y,
                                           const float (&gridv)[4], const float (&invgv)[4])
{
    if (ek == 0) {
        *(uint32_t*)&feat[ep][32] = pk_bf16(x, y);
        *(uint32_t*)&feat[ep][34] = 0u;
        *(uint32_t*)&feat[ep][36] = 0u;
        *(uint32_t*)&feat[ep][38] = 0u;
    }
    #pragma unroll
    for (int i = 0; i < 4; ++i) {
        const float grid = gridv[i], invg = invgv[i];
        const int bx = (int)floorf((x + 1.0f) / grid);
        const int by = (int)floorf((y + 1.0f) / grid);
        const float vx = (float)bx * grid - 1.0f;
        const float vy = (float)by * grid - 1.0f;
        const float wx = (x - vx) * invg;
        const float wy = (y - vy) * invg;
        const uint32_t u00 = g[4 * i + 0], u01 = g[4 * i + 1];
        const uint32_t u10 = g[4 * i + 2], u11 = g[4 * i + 3];
        const float e00x = __uint_as_float(u00 << 16), e00y = __uint_as_float(u00 & 0xffff0000u);
        const float e01x = __uint_as_float(u01 << 16), e01y = __uint_as_float(u01 & 0xffff0000u);
        const float e10x = __uint_as_float(u10 << 16), e10y = __uint_as_float(u10 & 0xffff0000u);
        const float e11x = __uint_as_float(u11 << 16), e11y = __uint_as_float(u11 & 0xffff0000u);
        const float owx = 1.f - wx, owy = 1.f - wy;
        const float f0 = (e00x * owx + e10x * wx) * owy + (e01x * owx + e11x * wx) * wy;
        const float f1 = (e00y * owx + e10y * wx) * owy + (e01y * owx + e11y * wx) * wy;
        *(uint32_t*)&feat[ep][8 * ek + 2 * i] = pk_bf16(f0, f1);
    }
}

// ---------------- fused, chunk-pipelined encode + MLP (spill-free, lgkm barriers) ----------------
__global__ __launch_bounds__(256, 2)
void fused_pipe(const float* __restrict__ coord,
                const uint32_t* __restrict__ tbl,
                const unsigned short* __restrict__ wpack,
                const float* __restrict__ b0,
                const float* __restrict__ b1,
                const float* __restrict__ b2,
                float* __restrict__ out, int npoints, int nchunks)
{
    __shared__ unsigned short feat[2][CPB][FROW];  // 10.25 KB double buffer
    __shared__ unsigned short h[CPB][HSTRIDE];     // 33.8 KB

    const int t = threadIdx.x;
    const int wave = t >> 6, lane = t & 63;
    const int q = lane >> 4, r = lane & 15;
    const int ep = t >> 2, ek = t & 3;             // encoder point / level-group

    const unsigned short* w0p = wpack;
    const unsigned short* w1p = wpack + 32 * 1024;
    const unsigned short* w2p = wpack + 160 * 1024;

    const int chunk0 = blockIdx.x * NCHUNK;
    if (chunk0 >= nchunks) return;

    // hoist per-thread level constants into registers once
    float resv[4], gridv[4], invgv[4];
    #pragma unroll
    for (int i = 0; i < 4; ++i) {
        resv[i]  = c_res[4 * ek + i];
        gridv[i] = 2.0f / resv[i];     // IEEE div, matches ref
        invgv[i] = resv[i] * 0.5f;     // exact
    }

    uint32_t g[16];
    float ncx, ncy;          // clamped coords of the chunk currently being gathered
    float nnx, nny;          // raw coords prefetched for the chunk after that

    // ---- prologue: encode chunk0 into feat[0], prefetch coords of chunk0+1 ----
    {
        const int gp = min(chunk0 * CPB + ep, npoints - 1);
        const float2 cc = *(const float2*)(coord + 2 * gp);
        ncx = fminf(fmaxf(cc.x, -1.f), 1.f);
        ncy = fminf(fmaxf(cc.y, -1.f), 1.f);
    }
    enc_issue(g, tbl, ncx, ncy, ek, gridv);
    {
        const int gp2 = min((chunk0 + 1) * CPB + ep, npoints - 1);
        const float2 c2 = *(const float2*)(coord + 2 * gp2);
        nnx = c2.x; nny = c2.y;
    }
    enc_commit(feat[0], ep, ek, g, ncx, ncy, gridv, invgv);
    ncx = fminf(fmaxf(nnx, -1.f), 1.f);
    ncy = fminf(fmaxf(nny, -1.f), 1.f);
    BARRIER_LGKM();

    for (int c = 0; c < NCHUNK; ++c) {
        const int chunk = chunk0 + c;
        if (chunk >= nchunks) break;               // block-uniform
        const int cur = c & 1;
        const bool have_next = (c + 1 < NCHUNK) && (chunk + 1 < nchunks);
        const int p0 = chunk * CPB;

        // ---- issue ALL early weight loads BEFORE the gathers, so weight waits
        //      never drain the gathers (vmcnt is in-order) ----
        short8 a0[4], a1[4];          // layer-0 fragments
        #pragma unroll
        for (int mti = 0; mti < 4; ++mti)
            a0[mti] = *(const short8*)(w0p + (size_t)(0 * 16 + wave * 4 + mti) * 1024 + lane * 8);
        #pragma unroll
        for (int mti = 0; mti < 4; ++mti)
            a1[mti] = *(const short8*)(w0p + (size_t)(1 * 16 + wave * 4 + mti) * 1024 + lane * 8);
        short8 awA[4], awB[4];        // layer-1 kt=0,1 fragments (2-deep pipeline)
        #pragma unroll
        for (int mti = 0; mti < 4; ++mti)
            awA[mti] = *(const short8*)(w1p + (size_t)(0 * 16 + wave * 4 + mti) * 1024 + lane * 8);
        #pragma unroll
        for (int mti = 0; mti < 4; ++mti)
            awB[mti] = *(const short8*)(w1p + (size_t)(1 * 16 + wave * 4 + mti) * 1024 + lane * 8);

        // ---- issue next chunk's gathers + coord prefetch for chunk+2 ----
        if (have_next) {
            enc_issue(g, tbl, ncx, ncy, ek, gridv);
            const int gp2 = min((chunk + 2) * CPB + ep, npoints - 1);
            const float2 c2 = *(const float2*)(coord + 2 * gp2);
            nnx = c2.x; nny = c2.y;
        }

        // ---- layer 0 (K=64 padded) -> h0[point][neuron] ----
        {
            floatx4 acc[4][4];
            #pragma unroll
            for (int mti = 0; mti < 4; ++mti)
                #pragma unroll
                for (int nt = 0; nt < 4; ++nt)
                    acc[mti][nt] = floatx4{0.f, 0.f, 0.f, 0.f};

            short8 b[4];
            #pragma unroll
            for (int nt = 0; nt < 4; ++nt)
                b[nt] = *(const short8*)&feat[cur][16 * nt + r][q * 8];
            #pragma unroll
            for (int mti = 0; mti < 4; ++mti)
                #pragma unroll
                for (int nt = 0; nt < 4; ++nt)
                    acc[mti][nt] = __builtin_amdgcn_mfma_f32_16x16x32_bf16(a0[mti], b[nt], acc[mti][nt], 0, 0, 0);
            #pragma unroll
            for (int nt = 0; nt < 4; ++nt)
                b[nt] = (q == 0) ? *(const short8*)&feat[cur][16 * nt + r][32]
                                 : short8{0,0,0,0,0,0,0,0};
            #pragma unroll
            for (int mti = 0; mti < 4; ++mti)
                #pragma unroll
                for (int nt = 0; nt < 4; ++nt)
                    acc[mti][nt] = __builtin_amdgcn_mfma_f32_16x16x32_bf16(a1[mti], b[nt], acc[mti][nt], 0, 0, 0);

            #pragma unroll
            for (int mti = 0; mti < 4; ++mti) {
                const int col = (wave * 4 + mti) * 16 + 4 * q;
                const float4 bias = *(const float4*)&b0[col];
                #pragma unroll
                for (int nt = 0; nt < 4; ++nt) {
                    const floatx4 a4 = acc[mti][nt];
                    uint2 v;
                    v.x = pk_bf16(fmaxf(a4[0] + bias.x, 0.f), fmaxf(a4[1] + bias.y, 0.f));
                    v.y = pk_bf16(fmaxf(a4[2] + bias.z, 0.f), fmaxf(a4[3] + bias.w, 0.f));
                    *(uint2*)&h[16 * nt + r][col] = v;
                }
            }
        }
        BARRIER_LGKM();

        // ---- layer 1 (256 -> 256), a-fragments software-pipelined 2 deep ----
        {
            floatx4 acc[4][4];
            #pragma unroll
            for (int mti = 0; mti < 4; ++mti)
                #pragma unroll
                for (int nt = 0; nt < 4; ++nt)
                    acc[mti][nt] = floatx4{0.f, 0.f, 0.f, 0.f};
            #pragma unroll
            for (int kt = 0; kt < 8; ++kt) {
                short8* acur = (kt & 1) ? awB : awA;
                short8 b[4];
                #pragma unroll
                for (int nt = 0; nt < 4; ++nt)
                    b[nt] = *(const short8*)&h[16 * nt + r][kt * 32 + q * 8];
                #pragma unroll
                for (int mti = 0; mti < 4; ++mti)
                    #pragma unroll
                    for (int nt = 0; nt < 4; ++nt)
                        acc[mti][nt] = __builtin_amdgcn_mfma_f32_16x16x32_bf16(acur[mti], b[nt], acc[mti][nt], 0, 0, 0);
                if (kt + 2 < 8) {
                    #pragma unroll
                    for (int mti = 0; mti < 4; ++mti)
                        acur[mti] = *(const short8*)(w1p + (size_t)((kt + 2) * 16 + wave * 4 + mti) * 1024 + lane * 8);
                }
            }
            BARRIER_LGKM();   // all reads of h0 done before overwrite
            #pragma unroll
            for (int mti = 0; mti < 4; ++mti) {
                const int col = (wave * 4 + mti) * 16 + 4 * q;
                const float4 bias = *(const float4*)&b1[col];
                #pragma unroll
                for (int nt = 0; nt < 4; ++nt) {
                    const floatx4 a4 = acc[mti][nt];
                    uint2 v;
                    v.x = pk_bf16(fmaxf(a4[0] + bias.x, 0.f), fmaxf(a4[1] + bias.y, 0.f));
                    v.y = pk_bf16(fmaxf(a4[2] + bias.z, 0.f), fmaxf(a4[3] + bias.w, 0.f));
                    *(uint2*)&h[16 * nt + r][col] = v;
                }
            }
        }
        BARRIER_LGKM();

        // ---- layer 2 (256 -> 3), sigmoid, store ----
        {
            floatx4 acc = floatx4{0.f, 0.f, 0.f, 0.f};
            #pragma unroll
            for (int kt = 0; kt < 8; ++kt) {
                const short8 a = *(const short8*)(w2p + (size_t)kt * 1024 + lane * 8);
                const short8 b = *(const short8*)&h[16 * wave + r][kt * 32 + q * 8];
                acc = __builtin_amdgcn_mfma_f32_16x16x32_bf16(a, b, acc, 0, 0, 0);
            }
            if (q == 0) {
                const int gp = p0 + 16 * wave + r;
                if (gp < npoints) {
                    #pragma unroll
                    for (int reg = 0; reg < 3; ++reg) {
                        const float sv = acc[reg] + b2[reg];
                        out[(size_t)gp * 3 + reg] = 1.f / (1.f + expf(-sv));
                    }
                }
            }
        }

        // ---- commit next chunk's features (gathers are long since landed) ----
        if (have_next) {
            enc_commit(feat[cur ^ 1], ep, ek, g, ncx, ncy, gridv, invgv);
            ncx = fminf(fmaxf(nnx, -1.f), 1.f);
            ncy = fminf(fmaxf(nny, -1.f), 1.f);
        }
        BARRIER_LGKM();
    }
}

// ---------------- fused fallback (fp32 table, no big ws needed) ----------------
__global__ __launch_bounds__(256, 2)
void fused_ngp_mlp(const float* __restrict__ coord,
                   const float* __restrict__ emb,
                   const unsigned short* __restrict__ wpack,
                   const float* __restrict__ b0,
                   const float* __restrict__ b1,
                   const float* __restrict__ b2,
                   float* __restrict__ out, int npoints)
{
    __shared__ unsigned short feat[64][FSTRIDE];
    __shared__ unsigned short h[64][HSTRIDE];

    const int t = threadIdx.x;
    const int p0 = blockIdx.x * 64;
    const int wave = t >> 6;
    const int lane = t & 63;
    const int q = lane >> 4, r = lane & 15;

    {
        const int p = t >> 2;
        const int k = t & 3;
        const int gp = min(p0 + p, npoints - 1);
        float x = coord[2 * gp + 0];
        float y = coord[2 * gp + 1];
        x = fminf(fmaxf(x, -1.f), 1.f);
        y = fminf(fmaxf(y, -1.f), 1.f);
        if (k == 0) {
            feat[p][32] = f2bf(x); feat[p][33] = f2bf(y);
            *(uint32_t*)&feat[p][34] = 0u;
            *(uint32_t*)&feat[p][36] = 0u;
            *(uint32_t*)&feat[p][38] = 0u;
        } else {
            const uint4 z = {0u, 0u, 0u, 0u};
            *(uint4*)&feat[p][40 + 8 * (k - 1)] = z;
        }
        #pragma unroll
        for (int i = 0; i < 4; ++i) {
            const int l = 4 * k + i;
            const float res  = c_res[l];
            const float grid = 2.0f / res;
            const float invg = res * 0.5f;
            const int bx = (int)floorf((x + 1.0f) / grid);
            const int by = (int)floorf((y + 1.0f) / grid);
            const float vx = (float)bx * grid - 1.0f;
            const float vy = (float)by * grid - 1.0f;
            const float wx = (x - vx) * invg;
            const float wy = (y - vy) * invg;
            const float2* tab = (const float2*)emb + (size_t)l * TABLE_SIZE;
            const uint32_t ux0 = (uint32_t)bx, ux1 = (uint32_t)(bx + 1);
            const uint32_t hy0 = (uint32_t)by * PRIME1;
            const uint32_t hy1 = (uint32_t)(by + 1) * PRIME1;
            const float2 e00 = tab[(ux0 ^ hy0) & HASH_MASK];
            const float2 e01 = tab[(ux0 ^ hy1) & HASH_MASK];
            const float2 e10 = tab[(ux1 ^ hy0) & HASH_MASK];
            const float2 e11 = tab[(ux1 ^ hy1) & HASH_MASK];
            const float owx = 1.f - wx, owy = 1.f - wy;
            const float f0 = (e00.x * owx + e10.x * wx) * owy + (e01.x * owx + e11.x * wx) * wy;
            const float f1 = (e00.y * owx + e10.y * wx) * owy + (e01.y * owx + e11.y * wx) * wy;
            *(uint32_t*)&feat[p][8 * k + 2 * i] = pk_bf16(f0, f1);
        }
    }
    __syncthreads();

    const unsigned short* w0p = wpack;
    const unsigned short* w1p = wpack + 32 * 1024;
    const unsigned short* w2p = wpack + 160 * 1024;

    {
        floatx4 acc[4][4];
        #pragma unroll
        for (int mti = 0; mti < 4; ++mti)
            #pragma unroll
            for (int nt = 0; nt < 4; ++nt)
                acc[mti][nt] = floatx4{0.f, 0.f, 0.f, 0.f};
        #pragma unroll
        for (int kt = 0; kt < 2; ++kt) {
            short8 a[4], b[4];
            #pragma unroll
            for (int mti = 0; mti < 4; ++mti)
                a[mti] = *(const short8*)(w0p + (size_t)(kt * 16 + wave * 4 + mti) * 1024 + lane * 8);
            #pragma unroll
            for (int nt = 0; nt < 4; ++nt)
                b[nt] = *(const short8*)&feat[16 * nt + r][kt * 32 + q * 8];
            #pragma unroll
            for (int mti = 0; mti < 4; ++mti)
                #pragma unroll
                for (int nt = 0; nt < 4; ++nt)
                    acc[mti][nt] = __builtin_amdgcn_mfma_f32_16x16x32_bf16(a[mti], b[nt], acc[mti][nt], 0, 0, 0);
        }
        #pragma unroll
        for (int mti = 0; mti < 4; ++mti) {
            const int col = (wave * 4 + mti) * 16 + 4 * q;
            const float4 bias = *(const float4*)&b0[col];
            #pragma unroll
            for (int nt = 0; nt < 4; ++nt) {
                const floatx4 a4 = acc[mti][nt];
                uint2 v;
                v.x = pk_bf16(fmaxf(a4[0] + bias.x, 0.f), fmaxf(a4[1] + bias.y, 0.f));
                v.y = pk_bf16(fmaxf(a4[2] + bias.z, 0.f), fmaxf(a4[3] + bias.w, 0.f));
                *(uint2*)&h[16 * nt + r][col] = v;
            }
        }
    }
    __syncthreads();

    {
        floatx4 acc[4][4];
        #pragma unroll
        for (int mti = 0; mti < 4; ++mti)
            #pragma unroll
            for (int nt = 0; nt < 4; ++nt)
                acc[mti][nt] = floatx4{0.f, 0.f, 0.f, 0.f};
        #pragma unroll 2
        for (int kt = 0; kt < 8; ++kt) {
            short8 a[4], b[4];
            #pragma unroll
            for (int mti = 0; mti < 4; ++mti)
                a[mti] = *(const short8*)(w1p + (size_t)(kt * 16 + wave * 4 + mti) * 1024 + lane * 8);
            #pragma unroll
            for (int nt = 0; nt < 4; ++nt)
                b[nt] = *(const short8*)&h[16 * nt + r][kt * 32 + q * 8];
            #pragma unroll
            for (int mti = 0; mti < 4; ++mti)
                #pragma unroll
                for (int nt = 0; nt < 4; ++nt)
                    acc[mti][nt] = __builtin_amdgcn_mfma_f32_16x16x32_bf16(a[mti], b[nt], acc[mti][nt], 0, 0, 0);
        }
        __syncthreads();
        #pragma unroll
        for (int mti = 0; mti < 4; ++mti) {
            const int col = (wave * 4 + mti) * 16 + 4 * q;
            const float4 bias = *(const float4*)&b1[col];
            #pragma unroll
            for (int nt = 0; nt < 4; ++nt) {
                const floatx4 a4 = acc[mti][nt];
                uint2 v;
                v.x = pk_bf16(fmaxf(a4[0] + bias.x, 0.f), fmaxf(a4[1] + bias.y, 0.f));
                v.y = pk_bf16(fmaxf(a4[2] + bias.z, 0.f), fmaxf(a4[3] + bias.w, 0.f));
                *(uint2*)&h[16 * nt + r][col] = v;
            }
        }
    }
    __syncthreads();

    {
        floatx4 acc = floatx4{0.f, 0.f, 0.f, 0.f};
        #pragma unroll
        for (int kt = 0; kt < 8; ++kt) {
            const short8 a = *(const short8*)(w2p + (size_t)kt * 1024 + lane * 8);
            const short8 b = *(const short8*)&h[16 * wave + r][kt * 32 + q * 8];
            acc = __builtin_amdgcn_mfma_f32_16x16x32_bf16(a, b, acc, 0, 0, 0);
        }
        if (q == 0) {
            const int gp = p0 + 16 * wave + r;
            if (gp < npoints) {
                #pragma unroll
                for (int reg = 0; reg < 3; ++reg) {
                    const float s = acc[reg] + b2[reg];
                    out[(size_t)gp * 3 + reg] = 1.f / (1.f + expf(-s));
                }
            }
        }
    }
}

extern "C" void kernel_launch(void* const* d_in, const int* in_sizes, int n_in,
                              void* d_out, int out_size, void* d_ws, size_t ws_size,
                              hipStream_t stream) {
    const float* coord = (const float*)d_in[0];
    const float* emb   = (const float*)d_in[1];
    const float* W0    = (const float*)d_in[2];
    const float* b0    = (const float*)d_in[3];
    const float* W1    = (const float*)d_in[4];
    const float* b1    = (const float*)d_in[5];
    const float* W2    = (const float*)d_in[6];
    const float* b2    = (const float*)d_in[7];
    float* out = (float*)d_out;

    const int npoints  = in_sizes[0] / 2;
    const int nentries = N_LEVELS * TABLE_SIZE;

    const size_t pack_bytes = 168u * 1024u * 2u;     // 344 KB
    const size_t tbl_bytes  = (size_t)nentries * 4u; // 33.5 MB

    unsigned short* wpack = (unsigned short*)d_ws;

    hipLaunchKernelGGL(pack_weights, dim3(168), dim3(64), 0, stream, W0, W1, W2, wpack);

    const int nchunks = (npoints + CPB - 1) / CPB;

    if (ws_size >= pack_bytes + tbl_bytes) {
        uint32_t* tbl = (uint32_t*)((char*)d_ws + pack_bytes);
        hipLaunchKernelGGL(convert_table, dim3((nentries / 4 + 255) / 256), dim3(256), 0, stream,
                           emb, tbl, nentries);
        const int grid = (nchunks + NCHUNK - 1) / NCHUNK;
        hipLaunchKernelGGL(fused_pipe, dim3(grid), dim3(256), 0, stream,
                           coord, tbl, wpack, b0, b1, b2, out, npoints, nchunks);
    } else {
        hipLaunchKernelGGL(fused_ngp_mlp, dim3(nchunks), dim3(256), 0, stream,
                           coord, emb, wpack, b0, b1, b2, out, npoints);
    }
}